// Round 10
// baseline (479.484 us; speedup 1.0000x reference)
//
#include <hip/hip_runtime.h>
#include <hip/hip_fp16.h>

// AffineCouplingBlock MI355X — Round 8b resubmit (round-9 bench was a GPU
// acquisition timeout, no signal). Swapped-operand MFMA, register-resident h.
// Every layer: mfma(A=W_frag, B=h_frag) -> C cols = points, rows = h-idx.
// Weight k-order sigma(kt,g,j)=32kt+16(j>>2)+4g+(j&3) makes next layer's B-frag a
// pure in-lane repack of this layer's acc (silu+cvt_pk) — NO LDS between layers.
// LDS only stages gather->comb (layer-0 B). Layer-3 fuses the f32 w2 dot.
// comb col layout (K-permuted in prep): [lf 0..63][cond 64..79][z 80][0 81..95]

#define NPTS (64 * 4096)
#define ZSIZE (NPTS * 2)

typedef _Float16 f16x8 __attribute__((ext_vector_type(8)));
typedef _Float16 f16x2 __attribute__((ext_vector_type(2)));
typedef __fp16 fp16x2 __attribute__((ext_vector_type(2)));
typedef float f32x4 __attribute__((ext_vector_type(4)));

// ws layout: W0f [4][3][8][{hi512,lo512}] | W1f [12][4][8][1024] | wt [64][64][64][64] f32
#define W0F_HALFS (4 * 3 * 8 * 1024)   // 98304
#define W1F_HALFS (12 * 4 * 8 * 1024)  // 393216
#define WT_BYTES_OFF ((W0F_HALFS + W1F_HALFS) * 2)  // 983040
#define WT_BYTES (64ull * 64 * 64 * 64 * 4)         // 67108864

// ---------------------------------------------------------------------------
// Prep 1: weights -> A-fragments (lane=16g+c holds row m=n0*16+c, k=8g+j slot).
// W0 (layer0): natural k = kt*32+8g+j (comb B-frags read from LDS in this order).
// W1 (layers1-3): k = sigma(kt,g,j) = 32kt+16(j>>2)+4g+(j&3) so the B-operand is
// the previous layer's acc repacked in-lane (acc rows n = 16n0+4g+rg).
// ---------------------------------------------------------------------------
__global__ void prep_kernel(const float* __restrict__ W0, const float* __restrict__ W1,
                            _Float16* __restrict__ W0f, _Float16* __restrict__ W1f,
                            float* __restrict__ out_ld) {
    const int t0 = blockIdx.x * blockDim.x + threadIdx.x;
    const int stride = gridDim.x * blockDim.x;
    if (t0 < 64) out_ld[t0] = 0.f;
    // W0: [4][128][81] -> padded K=96, col permutation (new k 0..79 <- old k+1, 80 <- old 0)
    for (int t = t0; t < 4 * 3 * 8 * 64 * 8; t += stride) {
        int j = t & 7, r = t >> 3;
        int l = r & 63; r >>= 6;
        int n0 = r & 7; r >>= 3;
        int kt = r % 3, idx = r / 3;
        int k = kt * 32 + (l >> 4) * 8 + j;
        int n = n0 * 16 + (l & 15);
        float v = 0.f;
        if (k <= 80) {
            int ko = (k < 80) ? (k + 1) : 0;
            v = W0[(idx * 128 + n) * 81 + ko];
        }
        _Float16 hi = (_Float16)v;
        _Float16 lo = (_Float16)(v - (float)hi);
        int base = ((idx * 3 + kt) * 8 + n0) * 1024;
        W0f[base + l * 8 + j] = hi;
        W0f[base + 512 + l * 8 + j] = lo;
    }
    // W1: [12][128][128], sigma k-order
    for (int t = t0; t < 12 * 4 * 8 * 64 * 8; t += stride) {
        int j = t & 7, r = t >> 3;
        int l = r & 63; r >>= 6;
        int n0 = r & 7; r >>= 3;
        int kt = r & 3, m = r >> 2;
        int k = kt * 32 + ((j >> 2) << 4) + ((l >> 4) << 2) + (j & 3);  // sigma
        int n = n0 * 16 + (l & 15);
        float v = W1[(m * 128 + n) * 128 + k];
        _Float16 hi = (_Float16)v;
        _Float16 lo = (_Float16)(v - (float)hi);
        int base = ((m * 4 + kt) * 8 + n0) * 1024;
        W1f[base + l * 8 + j] = hi;
        W1f[base + 512 + l * 8 + j] = lo;
    }
}

// ---------------------------------------------------------------------------
// Prep 2: transpose w [B,C,H,W] -> wt [B,H,W,C] (f32) via LDS tile.
// ---------------------------------------------------------------------------
__global__ __launch_bounds__(256) void transpose_w(const float* __restrict__ w,
                                                   float* __restrict__ wt) {
    __shared__ float t[64][65];
    const int by = blockIdx.x;  // b*64 + y
    const int y = by & 63, b = by >> 6;
    const int c4 = threadIdx.x >> 6, xx = threadIdx.x & 63;
    const float* src = w + ((size_t)b << 18) + ((size_t)y << 6);
#pragma unroll
    for (int i = 0; i < 16; ++i) {
        const int c = i * 4 + c4;
        t[c][xx] = src[((size_t)c << 12) + xx];
    }
    __syncthreads();
    float* dst = wt + ((size_t)b << 18) + ((size_t)y << 12);
#pragma unroll
    for (int i = 0; i < 16; ++i) {
        const int xo = i * 4 + c4;
        dst[(xo << 6) + xx] = t[xx][xo];
    }
}

// ---------------------------------------------------------------------------
__device__ __forceinline__ float silu(float v) {
    return v * __builtin_amdgcn_rcpf(1.f + __expf(-v));
}

__device__ __forceinline__ f16x2 cvt2(float a, float b) {
    union {
        fp16x2 n;   // builtin's native return type
        f16x2 t;    // our _Float16 vector (bit-identical IEEE half)
    } u;
    u.n = __builtin_amdgcn_cvt_pkrtz(a, b);
    return u.t;
}

// pack silu(acc[n0=2kt]) rg0..3 | silu(acc[n0=2kt+1]) rg0..3 -> B-frag slot order
__device__ __forceinline__ f16x8 pack_silu(f32x4 aA, f32x4 aB) {
    union {
        f16x2 h2[4];
        f16x8 v;
    } u;
    u.h2[0] = cvt2(silu(aA[0]), silu(aA[1]));
    u.h2[1] = cvt2(silu(aA[2]), silu(aA[3]));
    u.h2[2] = cvt2(silu(aB[0]), silu(aB[1]));
    u.h2[3] = cvt2(silu(aB[2]), silu(aB[3]));
    return u.v;
}

// One layer, swapped operands: acc[pt][n0] (+= bias) = W(n0-block) x Bin[pt].
template <bool LO, int KT>
__device__ __forceinline__ void layer_mfma(const _Float16* __restrict__ wfb,
                                           const float* __restrict__ bias,
                                           const f16x8 (*Bin)[4], f32x4 (*acc)[8], int lane,
                                           int fg) {
#pragma unroll
    for (int n0 = 0; n0 < 8; ++n0) {
        f16x8 Ah[KT];
        f16x8 Al[KT];
#pragma unroll
        for (int kt = 0; kt < KT; ++kt) {
            const _Float16* c2 = wfb + (kt * 8 + n0) * 1024 + lane * 8;
            Ah[kt] = *(const f16x8*)c2;
            if (LO) Al[kt] = *(const f16x8*)(c2 + 512);
        }
        const f32x4 b4 = *(const f32x4*)(bias + n0 * 16 + 4 * fg);
        f32x4 a0 = b4, a1 = b4;
#pragma unroll
        for (int kt = 0; kt < KT; ++kt) {
            a0 = __builtin_amdgcn_mfma_f32_16x16x32_f16(Ah[kt], Bin[0][kt], a0, 0, 0, 0);
            a1 = __builtin_amdgcn_mfma_f32_16x16x32_f16(Ah[kt], Bin[1][kt], a1, 0, 0, 0);
            if (LO) {
                a0 = __builtin_amdgcn_mfma_f32_16x16x32_f16(Al[kt], Bin[0][kt], a0, 0, 0, 0);
                a1 = __builtin_amdgcn_mfma_f32_16x16x32_f16(Al[kt], Bin[1][kt], a1, 0, 0, 0);
            }
        }
        acc[0][n0] = a0;
        acc[1][n0] = a1;
    }
}

// Full 4-layer MLP + fused w2 dot. Returns y for (point=fr, point=16+fr).
template <bool LO>
__device__ __forceinline__ float2 mlp_chain(int idx, const _Float16* __restrict__ comb,
                                            const _Float16* __restrict__ W0f,
                                            const float* __restrict__ b0,
                                            const _Float16* __restrict__ W1f,
                                            const float* __restrict__ b1,
                                            const float* __restrict__ W2,
                                            const float* __restrict__ b2, int lane, int fr,
                                            int fg) {
    f32x4 acc[2][8];
    {
        f16x8 cB[2][4];
#pragma unroll
        for (int pt = 0; pt < 2; ++pt)
#pragma unroll
            for (int kt = 0; kt < 3; ++kt)
                cB[pt][kt] = *(const f16x8*)(comb + (pt * 16 + fr) * 104 + kt * 32 + fg * 8);
        layer_mfma<LO, 3>(W0f + idx * 3 * 8192, b0 + idx * 128, cB, acc, lane, fg);
    }
    f16x8 hB[2][4];
#pragma unroll
    for (int l = 0; l < 3; ++l) {
#pragma unroll
        for (int pt = 0; pt < 2; ++pt)
#pragma unroll
            for (int kt = 0; kt < 4; ++kt)
                hB[pt][kt] = pack_silu(acc[pt][2 * kt], acc[pt][2 * kt + 1]);
        layer_mfma<LO, 4>(W1f + (idx * 3 + l) * 32768, b1 + (idx * 3 + l) * 128, hB, acc, lane,
                          fg);
    }
    // fused output dot: y[p] = sum_n silu(h3[n][p]) * w2[n] + b2 (f32)
    float d0 = 0.f, d1 = 0.f;
#pragma unroll
    for (int n0 = 0; n0 < 8; ++n0) {
        const f32x4 w2v = *(const f32x4*)(W2 + idx * 128 + n0 * 16 + 4 * fg);
#pragma unroll
        for (int rg = 0; rg < 4; ++rg) {
            d0 = fmaf(silu(acc[0][n0][rg]), w2v[rg], d0);
            d1 = fmaf(silu(acc[1][n0][rg]), w2v[rg], d1);
        }
    }
    d0 += __shfl_xor(d0, 16);
    d0 += __shfl_xor(d0, 32);
    d1 += __shfl_xor(d1, 16);
    d1 += __shfl_xor(d1, 32);
    const float b2v = b2[idx];
    return make_float2(d0 + b2v, d1 + b2v);
}

template <bool FIRST>
__device__ __forceinline__ void tap_acc(float* lf, const float* __restrict__ tp, float f) {
#pragma unroll
    for (int r = 0; r < 8; ++r) {
        const f32x4 v = *(const f32x4*)(tp + 4 * r);
#pragma unroll
        for (int j = 0; j < 4; ++j)
            lf[4 * r + j] = FIRST ? f * v[j] : fmaf(f, v[j], lf[4 * r + j]);
    }
    __builtin_amdgcn_sched_barrier(0);  // cap gather load-hoisting (VGPR control)
}

// ---------------------------------------------------------------------------
// Fused kernel: both stages. 2 waves/block, 32 points/wave; LDS = comb staging
// only (wave-private, in-order DS pipe -> no barriers anywhere).
// ---------------------------------------------------------------------------
__global__ __launch_bounds__(128, 2) void fused_kernel(
    const float* __restrict__ x, const float* __restrict__ wt, const float* __restrict__ cond,
    const _Float16* __restrict__ W0f, const float* __restrict__ b0,
    const _Float16* __restrict__ W1f, const float* __restrict__ b1,
    const float* __restrict__ W2, const float* __restrict__ b2, float* __restrict__ out) {
    __shared__ __align__(16) _Float16 clds[2][32][104];  // 13312 B

    const int o = blockIdx.x;
    const int wg = (o & 7) * 512 + (o >> 3);  // XCD-bijective swizzle (4096 = 8*512)
    const int tid = threadIdx.x;
    const int wv = tid >> 6, lane = tid & 63;
    const int pl = lane & 31;  // this lane's point
    const int hh = lane >> 5;  // channel-half for gather
    const int fr = lane & 15, fg = lane >> 4;
    const int pbase = wg * 64 + wv * 32;
    const int b = wg >> 6;  // 64 blocks (4096 points) per batch

    const float2 xv = *(const float2*)&x[2 * (pbase + pl)];
    const float xa = xv.x, xb = xv.y;
    float za = 0.f, zb = 0.f;

    __half2 cpk[8];
    {
        const float* cb = cond + b * 16;
#pragma unroll
        for (int j = 0; j < 8; ++j) cpk[j] = __floats2half2_rn(cb[2 * j], cb[2 * j + 1]);
    }

    float s_acc = 0.f;

    for (int stage = 0; stage < 2; ++stage) {
        // ---- bilinear params ----
        const float cx = stage ? za : xa;  // grid x = cur_z[...,0]
        const float cy = xb;               // grid y = z_b
        const float gx = cx * 2.f - 1.f, gy = cy * 2.f - 1.f;
        const float ixf = (gx + 1.f) * 0.5f * 63.f;
        const float iyf = (gy + 1.f) * 0.5f * 63.f;
        const float ix0f = floorf(ixf), iy0f = floorf(iyf);
        const float ix1f = ix0f + 1.f, iy1f = iy0f + 1.f;
        const float wx1 = ixf - ix0f, wx0 = 1.f - wx1;
        const float wy1 = iyf - iy0f, wy0 = 1.f - wy1;
        const bool vx0 = (ix0f >= 0.f) && (ix0f <= 63.f);
        const bool vx1 = (ix1f >= 0.f) && (ix1f <= 63.f);
        const bool vy0 = (iy0f >= 0.f) && (iy0f <= 63.f);
        const bool vy1 = (iy1f >= 0.f) && (iy1f <= 63.f);
        const float f00 = (vy0 && vx0) ? wy0 * wx0 : 0.f;
        const float f01 = (vy0 && vx1) ? wy0 * wx1 : 0.f;
        const float f10 = (vy1 && vx0) ? wy1 * wx0 : 0.f;
        const float f11 = (vy1 && vx1) ? wy1 * wx1 : 0.f;
        const int xi0 = (int)fminf(fmaxf(ix0f, 0.f), 63.f);
        const int xi1 = (int)fminf(fmaxf(ix1f, 0.f), 63.f);
        const int yi0 = (int)fminf(fmaxf(iy0f, 0.f), 63.f);
        const int yi1 = (int)fminf(fmaxf(iy1f, 0.f), 63.f);
        const int o00 = yi0 * 64 + xi0, o01 = yi0 * 64 + xi1;
        const int o10 = yi1 * 64 + xi0, o11 = yi1 * 64 + xi1;

        // ---- contiguous-channel gather (wt [B,H,W,C] f32), 32 ch per lane ----
        {
            const float* wtb = wt + ((size_t)b << 18) + hh * 32;
            float lf[32];
            tap_acc<true>(lf, wtb + ((size_t)o00 << 6), f00);
            tap_acc<false>(lf, wtb + ((size_t)o01 << 6), f01);
            tap_acc<false>(lf, wtb + ((size_t)o10 << 6), f10);
            tap_acc<false>(lf, wtb + ((size_t)o11 << 6), f11);
#pragma unroll
            for (int j = 0; j < 16; ++j)
                *(__half2*)&clds[wv][pl][hh * 32 + 2 * j] =
                    __floats2half2_rn(lf[2 * j], lf[2 * j + 1]);
        }
        if (hh == 0) {  // cond 64..79, z_keep 80, zeros 81..95 (keep pad finite!)
            const float zk = stage ? za : xb;
#pragma unroll
            for (int j2 = 0; j2 < 8; ++j2) *(__half2*)&clds[wv][pl][64 + 2 * j2] = cpk[j2];
            *(__half2*)&clds[wv][pl][80] = __floats2half2_rn(zk, 0.f);
#pragma unroll
            for (int j2 = 41; j2 < 48; ++j2)
                *(__half2*)&clds[wv][pl][2 * j2] = __floats2half2_rn(0.f, 0.f);
        }

        // ---- both MLP chains (s: hi/lo weights, t: hi only) ----
        const _Float16* comb = &clds[wv][0][0];
        const float2 ys2 = mlp_chain<true>(stage * 2 + 0, comb, W0f, b0, W1f, b1, W2, b2, lane,
                                           fr, fg);
        const float2 yt2 = mlp_chain<false>(stage * 2 + 1, comb, W0f, b0, W1f, b1, W2, b2, lane,
                                            fr, fg);

        // lane's point pl: tile0 (pl<16, col fr=pl) or tile1 (pl>=16, col fr=pl-16)
        const float ys = (pl < 16) ? ys2.x : ys2.y;
        const float yt = (pl < 16) ? yt2.x : yt2.y;
        const float s = 1.5f * (1.f - 2.f * __builtin_amdgcn_rcpf(__expf(2.f * ys) + 1.f));
        if (stage == 0)
            za = fmaf(xa, __expf(s), yt);
        else
            zb = fmaf(xb, __expf(s), yt);
        if (hh == 0) s_acc += s;
    }

    if (hh == 0) *(float2*)&out[2 * (pbase + pl)] = make_float2(za, zb);

    float r = s_acc;
#pragma unroll
    for (int off = 1; off <= 32; off <<= 1) r += __shfl_xor(r, off);
    if (lane == 0) atomicAdd(out + ZSIZE + b, r);
}

// ---------------------------------------------------------------------------
extern "C" void kernel_launch(void* const* d_in, const int* in_sizes, int n_in,
                              void* d_out, int out_size, void* d_ws, size_t ws_size,
                              hipStream_t stream) {
    const float* x = (const float*)d_in[0];
    const float* w = (const float*)d_in[1];
    const float* cond = (const float*)d_in[2];
    const float* W0 = (const float*)d_in[3];
    const float* b0 = (const float*)d_in[4];
    const float* W1 = (const float*)d_in[5];
    const float* b1 = (const float*)d_in[6];
    const float* W2 = (const float*)d_in[7];
    const float* b2 = (const float*)d_in[8];
    float* out = (float*)d_out;

    _Float16* W0f = (_Float16*)d_ws;
    _Float16* W1f = W0f + W0F_HALFS;
    float* wt = (float*)((char*)d_ws + WT_BYTES_OFF);

    prep_kernel<<<256, 256, 0, stream>>>(W0, W1, W0f, W1f, out + ZSIZE);
    transpose_w<<<4096, 256, 0, stream>>>(w, wt);
    fused_kernel<<<4096, 128, 0, stream>>>(x, wt, cond, W0f, b0, W1f, b1, W2, b2, out);
}